// Round 1
// baseline (2646.057 us; speedup 1.0000x reference)
//
#include <hip/hip_runtime.h>
#include <stdint.h>
#include <string.h>
#include <math.h>

#define NB 128   // batch
#define NN 512   // nodes
#define NH 256   // hidden
#define NR 3

// ======================= numpy RNG reproduction (host) =======================
struct Pcg {
  __uint128_t state, inc;
  bool has32; uint32_t buf32;
};

static const __uint128_t PCG_MULT =
    (((__uint128_t)2549297995355413924ULL) << 64) | 4865540595714422341ULL;

static inline uint64_t pcg_next64(Pcg& s) {
  s.state = s.state * PCG_MULT + s.inc;
  uint64_t hi = (uint64_t)(s.state >> 64), lo = (uint64_t)s.state;
  uint64_t x = hi ^ lo;
  unsigned rot = (unsigned)(s.state >> 122) & 63u;
  return (x >> rot) | (x << ((64u - rot) & 63u));
}
static inline uint32_t pcg_next32(Pcg& s) {
  if (s.has32) { s.has32 = false; return s.buf32; }
  uint64_t n = pcg_next64(s);
  s.has32 = true; s.buf32 = (uint32_t)(n >> 32);
  return (uint32_t)n;
}
// Generator.integers(0, high), int64 path -> Lemire32 (high-1 <= 0xFFFFFFFF)
static inline uint64_t pcg_bounded(Pcg& s, uint64_t high) {
  uint64_t rng = high - 1;
  if (rng == 0) return 0;  // no draw consumed
  uint32_t rng_excl = (uint32_t)rng + 1u;
  uint64_t m = (uint64_t)pcg_next32(s) * (uint64_t)rng_excl;
  uint32_t leftover = (uint32_t)m;
  if (leftover < rng_excl) {
    uint32_t threshold = (uint32_t)((0xFFFFFFFFu - (uint32_t)rng) % rng_excl);
    while (leftover < threshold) {
      m = (uint64_t)pcg_next32(s) * (uint64_t)rng_excl;
      leftover = (uint32_t)m;
    }
  }
  return m >> 32;
}
static inline double pcg_double(Pcg& s) {
  return (double)(pcg_next64(s) >> 11) * (1.0 / 9007199254740992.0);
}

// SeedSequence(0).generate_state(4, uint64) -> pcg64_set_seed
static void pcg_seed0(Pcg& s) {
  uint32_t pool[4];
  uint32_t hc = 0x43b0d7e5u;  // INIT_A
  auto hashmix = [&hc](uint32_t v) -> uint32_t {
    v ^= hc; hc *= 0x931e8875u; v *= hc; v ^= v >> 16; return v;
  };
  auto mix = [](uint32_t x, uint32_t y) -> uint32_t {
    uint32_t r = 0xca01f9ddu * x - 0x4973f715u * y; r ^= r >> 16; return r;
  };
  // entropy = [0], pool_size = 4
  for (int i = 0; i < 4; i++) pool[i] = hashmix(0u);
  for (int src = 0; src < 4; src++)
    for (int dst = 0; dst < 4; dst++)
      if (src != dst) pool[dst] = mix(pool[dst], hashmix(pool[src]));
  uint32_t gs[8]; uint32_t hb = 0x8b51f9ddu;  // INIT_B
  for (int i = 0; i < 8; i++) {
    uint32_t dv = pool[i & 3];
    dv ^= hb; hb *= 0x58f38dedu; dv *= hb; dv ^= dv >> 16;
    gs[i] = dv;
  }
  uint64_t w0 = (uint64_t)gs[0] | ((uint64_t)gs[1] << 32);
  uint64_t w1 = (uint64_t)gs[2] | ((uint64_t)gs[3] << 32);
  uint64_t w2 = (uint64_t)gs[4] | ((uint64_t)gs[5] << 32);
  uint64_t w3 = (uint64_t)gs[6] | ((uint64_t)gs[7] << 32);
  __uint128_t initstate = (((__uint128_t)w0) << 64) | w1;  // seed[0] is HIGH
  __uint128_t initseq   = (((__uint128_t)w2) << 64) | w3;
  s.state = 0;
  s.inc = (initseq << 1) | 1;
  s.state = s.state * PCG_MULT + s.inc;
  s.state += initstate;
  s.state = s.state * PCG_MULT + s.inc;
  s.has32 = false; s.buf32 = 0;
}

// ======================= tree build (host) =======================
struct TreeMeta {
  int nodes[512];   // internal nodes, ordered by level (deepest first), node id asc
  int cstart[512];
  int ccount[512];
  int echild[512];  // flat edges in node order
  int erel[512];
  float edecay[512];
};
struct HostTree {
  TreeMeta meta;
  int n_levels;
  int level_off[520];
  int level_M[520];
};

static void build_tree_host(HostTree& T) {
  Pcg st; pcg_seed0(st);
  int parent[NN], depth[NN], rel[NN];
  unsigned char virt[NN];
  parent[0] = 0; depth[0] = 0;
  for (int i = 1; i < NN; i++) parent[i] = (int)pcg_bounded(st, (uint64_t)i);
  for (int i = 1; i < NN; i++) depth[i] = depth[parent[i]] + 1;
  for (int i = 0; i < NN; i++) rel[i] = (int)pcg_bounded(st, (uint64_t)NR);
  for (int i = 0; i < NN; i++) virt[i] = (pcg_double(st) < 0.1) ? 1 : 0;

  int childcnt[NN]; memset(childcnt, 0, sizeof(childcnt));
  for (int i = 1; i < NN; i++) childcnt[parent[i]]++;
  int maxd = 0;
  for (int i = 0; i < NN; i++) if (depth[i] > maxd) maxd = depth[i];

  int ni = 0, ne = 0;
  T.n_levels = 0;
  for (int d = maxd; d >= 0; d--) {
    int mstart = ni;
    for (int n = 0; n < NN; n++) {
      if (depth[n] == d && childcnt[n] > 0) {
        T.meta.nodes[ni] = n;
        T.meta.cstart[ni] = ne;
        T.meta.ccount[ni] = childcnt[n];
        for (int i2 = 1; i2 < NN; i2++) {
          if (parent[i2] == n) {
            T.meta.echild[ne] = i2;
            T.meta.erel[ne] = rel[i2];
            T.meta.edecay[ne] = virt[i2] ? 0.7f : 1.0f;
            ne++;
          }
        }
        ni++;
      }
    }
    if (ni > mstart) {
      T.level_off[T.n_levels] = mstart;
      T.level_M[T.n_levels] = ni - mstart;
      T.n_levels++;
    }
  }
}

// ======================= kernels =======================
// Encoder GEMM: C[row, n] = sum_k A[row,k] * W[k,n] + bias[n]; rows = NB*NN
__global__ __launch_bounds__(256) void k_encoder(const float* __restrict__ A,
    const float* __restrict__ W, const float* __restrict__ bias,
    float* __restrict__ C) {
  __shared__ float As[16][65];
  __shared__ float Ws[16][65];
  const int bm = blockIdx.x * 64, bn = blockIdx.y * 64;
  const int tid = threadIdx.x;
  const int tm = tid & 15, tn = tid >> 4;
  const int lr = tid >> 2, lk = (tid & 3) << 2;
  const int wk = tid >> 4, wn = (tid & 15) << 2;
  float acc[4][4] = {};
  for (int k0 = 0; k0 < NH; k0 += 16) {
    const float* ap = A + (size_t)(bm + lr) * NH + k0 + lk;
    As[lk + 0][lr] = ap[0]; As[lk + 1][lr] = ap[1];
    As[lk + 2][lr] = ap[2]; As[lk + 3][lr] = ap[3];
    const float* wp = W + (size_t)(k0 + wk) * NH + bn + wn;
    Ws[wk][wn + 0] = wp[0]; Ws[wk][wn + 1] = wp[1];
    Ws[wk][wn + 2] = wp[2]; Ws[wk][wn + 3] = wp[3];
    __syncthreads();
#pragma unroll
    for (int k = 0; k < 16; k++) {
      float av[4], wv[4];
#pragma unroll
      for (int i = 0; i < 4; i++) av[i] = As[k][tm + 16 * i];
#pragma unroll
      for (int j = 0; j < 4; j++) wv[j] = Ws[k][tn + 16 * j];
#pragma unroll
      for (int i = 0; i < 4; i++)
#pragma unroll
        for (int j = 0; j < 4; j++) acc[i][j] = fmaf(av[i], wv[j], acc[i][j]);
    }
    __syncthreads();
  }
#pragma unroll
  for (int i = 0; i < 4; i++) {
    const size_t row = bm + tm + 16 * i;
#pragma unroll
    for (int j = 0; j < 4; j++) {
      const int col = bn + tn + 16 * j;
      C[row * NH + col] = acc[i][j] + bias[col];
    }
  }
}

// Attention + comb build. block = (m, b), 256 threads (one per hidden dim)
__global__ __launch_bounds__(256) void k_attn(const float* __restrict__ h,
    const float* __restrict__ rel_emb, const float* __restrict__ w_attn,
    const float* __restrict__ b_attn, float* __restrict__ comb,
    const int* __restrict__ nodes, const int* __restrict__ cstart,
    const int* __restrict__ ccount, const int* __restrict__ echild,
    const int* __restrict__ erel, const float* __restrict__ edecay,
    int node_base, int Mc) {
  const int m = blockIdx.x, b = blockIdx.y, t = threadIdx.x;
  const int nd = nodes[node_base + m];
  const int cs = cstart[node_base + m], cc = ccount[node_base + m];
  __shared__ float red[4];
  __shared__ float sc[64];
  const float wa = w_attn[t];
  const float ba = b_attn[0];
  for (int e = 0; e < cc; e++) {
    const int ch = echild[cs + e];
    const int r = erel[cs + e];
    const float dec = edecay[cs + e];
    float p = (rel_emb[r * NH + t] + h[((size_t)b * NN + ch) * NH + t] * dec) * wa;
#pragma unroll
    for (int off = 32; off; off >>= 1) p += __shfl_down(p, off);
    if ((t & 63) == 0) red[t >> 6] = p;
    __syncthreads();
    if (t == 0) sc[e] = red[0] + red[1] + red[2] + red[3] + ba;
    __syncthreads();
  }
  float mx = -1e30f;
  for (int e = 0; e < cc; e++) mx = fmaxf(mx, sc[e]);
  float ssum = 0.f;
  for (int e = 0; e < cc; e++) ssum += expf(sc[e] - mx);
  const float inv = 1.0f / ssum;
  float hsum = 0.f;
  for (int e = 0; e < cc; e++) {
    const int ch = echild[cs + e];
    const float dec = edecay[cs + e];
    const float w = expf(sc[e] - mx) * inv;
    hsum = fmaf(w * dec, h[((size_t)b * NN + ch) * NH + t], hsum);
  }
  const float x = h[((size_t)b * NN + nd) * NH + t];
  float* cb = comb + ((size_t)b * Mc + m) * (2 * NH);
  cb[t] = x;
  cb[NH + t] = hsum;
}

// Forget-gate GEMM + c_sum. block = (m, tile of 64 batch x 64 cols)
__global__ __launch_bounds__(256) void k_csum(const float* __restrict__ h,
    float* __restrict__ c, const float* __restrict__ W_f,
    const float* __restrict__ b_f,
    const int* __restrict__ nodes, const int* __restrict__ cstart,
    const int* __restrict__ ccount, const int* __restrict__ echild,
    const int* __restrict__ erel, const float* __restrict__ edecay,
    int node_base) {
  __shared__ float As[16][65];
  __shared__ float Ws[16][65];
  const int m = blockIdx.x;
  const int b0 = (blockIdx.y >> 2) * 64;
  const int n0 = (blockIdx.y & 3) * 64;
  const int tid = threadIdx.x;
  const int tm = tid & 15, tn = tid >> 4;
  const int lr = tid >> 2, lk = (tid & 3) << 2;
  const int wk = tid >> 4, wn = (tid & 15) << 2;
  const int nd = nodes[node_base + m];
  const int cs = cstart[node_base + m], cc = ccount[node_base + m];
  float csum[4][4] = {};
  for (int e = 0; e < cc; e++) {
    const int ch = echild[cs + e];
    const int r = erel[cs + e];
    const float dec = edecay[cs + e];
    const float* Wr = W_f + (size_t)r * NH * NH;
    float facc[4][4] = {};
    for (int k0 = 0; k0 < NH; k0 += 16) {
      const float* ap = h + ((size_t)(b0 + lr) * NN + ch) * NH + k0 + lk;
      As[lk + 0][lr] = ap[0] * dec; As[lk + 1][lr] = ap[1] * dec;
      As[lk + 2][lr] = ap[2] * dec; As[lk + 3][lr] = ap[3] * dec;
      const float* wp = Wr + (size_t)(k0 + wk) * NH + n0 + wn;
      Ws[wk][wn + 0] = wp[0]; Ws[wk][wn + 1] = wp[1];
      Ws[wk][wn + 2] = wp[2]; Ws[wk][wn + 3] = wp[3];
      __syncthreads();
#pragma unroll
      for (int k = 0; k < 16; k++) {
        float av[4], wv[4];
#pragma unroll
        for (int i = 0; i < 4; i++) av[i] = As[k][tm + 16 * i];
#pragma unroll
        for (int j = 0; j < 4; j++) wv[j] = Ws[k][tn + 16 * j];
#pragma unroll
        for (int i = 0; i < 4; i++)
#pragma unroll
          for (int j = 0; j < 4; j++) facc[i][j] = fmaf(av[i], wv[j], facc[i][j]);
      }
      __syncthreads();
    }
#pragma unroll
    for (int i = 0; i < 4; i++) {
      const int bb = b0 + tm + 16 * i;
#pragma unroll
      for (int j = 0; j < 4; j++) {
        const int col = n0 + tn + 16 * j;
        const float chc = c[((size_t)bb * NN + ch) * NH + col] * dec;
        csum[i][j] = fmaf(facc[i][j] + b_f[r * NH + col], chc, csum[i][j]);
      }
    }
  }
#pragma unroll
  for (int i = 0; i < 4; i++) {
    const int bb = b0 + tm + 16 * i;
#pragma unroll
    for (int j = 0; j < 4; j++) {
      const int col = n0 + tn + 16 * j;
      c[((size_t)bb * NN + nd) * NH + col] = csum[i][j];
    }
  }
}

// Gates: fused i/o/u GEMM (K=512 over comb) + LSTM epilogue
__global__ __launch_bounds__(256) void k_gates(const float* __restrict__ comb,
    const float* __restrict__ W_i, const float* __restrict__ b_i,
    const float* __restrict__ W_o, const float* __restrict__ b_o,
    const float* __restrict__ W_u, const float* __restrict__ b_u,
    float* __restrict__ h, float* __restrict__ c,
    const int* __restrict__ nodes, int node_base, int Mc) {
  __shared__ float As[16][65];
  __shared__ float Wis[16][65], Wos[16][65], Wus[16][65];
  const int m = blockIdx.x;
  const int b0 = (blockIdx.y >> 2) * 64;
  const int n0 = (blockIdx.y & 3) * 64;
  const int tid = threadIdx.x;
  const int tm = tid & 15, tn = tid >> 4;
  const int lr = tid >> 2, lk = (tid & 3) << 2;
  const int wk = tid >> 4, wn = (tid & 15) << 2;
  const int nd = nodes[node_base + m];
  float ai[4][4] = {}, ao[4][4] = {}, au[4][4] = {};
  for (int k0 = 0; k0 < 2 * NH; k0 += 16) {
    const float* ap = comb + ((size_t)(b0 + lr) * Mc + m) * (2 * NH) + k0 + lk;
    As[lk + 0][lr] = ap[0]; As[lk + 1][lr] = ap[1];
    As[lk + 2][lr] = ap[2]; As[lk + 3][lr] = ap[3];
    const size_t woff = (size_t)(k0 + wk) * NH + n0 + wn;
    const float* p1 = W_i + woff;
    Wis[wk][wn + 0] = p1[0]; Wis[wk][wn + 1] = p1[1];
    Wis[wk][wn + 2] = p1[2]; Wis[wk][wn + 3] = p1[3];
    const float* p2 = W_o + woff;
    Wos[wk][wn + 0] = p2[0]; Wos[wk][wn + 1] = p2[1];
    Wos[wk][wn + 2] = p2[2]; Wos[wk][wn + 3] = p2[3];
    const float* p3 = W_u + woff;
    Wus[wk][wn + 0] = p3[0]; Wus[wk][wn + 1] = p3[1];
    Wus[wk][wn + 2] = p3[2]; Wus[wk][wn + 3] = p3[3];
    __syncthreads();
#pragma unroll
    for (int k = 0; k < 16; k++) {
      float av[4];
#pragma unroll
      for (int i = 0; i < 4; i++) av[i] = As[k][tm + 16 * i];
#pragma unroll
      for (int j = 0; j < 4; j++) {
        const float wi = Wis[k][tn + 16 * j];
        const float wo = Wos[k][tn + 16 * j];
        const float wu = Wus[k][tn + 16 * j];
#pragma unroll
        for (int i = 0; i < 4; i++) {
          ai[i][j] = fmaf(av[i], wi, ai[i][j]);
          ao[i][j] = fmaf(av[i], wo, ao[i][j]);
          au[i][j] = fmaf(av[i], wu, au[i][j]);
        }
      }
    }
    __syncthreads();
  }
#pragma unroll
  for (int i = 0; i < 4; i++) {
    const int bb = b0 + tm + 16 * i;
#pragma unroll
    for (int j = 0; j < 4; j++) {
      const int col = n0 + tn + 16 * j;
      const float ig = 1.0f / (1.0f + expf(-(ai[i][j] + b_i[col])));
      const float og = 1.0f / (1.0f + expf(-(ao[i][j] + b_o[col])));
      const float ug = tanhf(au[i][j] + b_u[col]);
      const size_t idx = ((size_t)bb * NN + nd) * NH + col;
      const float cn = fmaf(ig, ug, c[idx]);
      c[idx] = cn;
      h[idx] = og * tanhf(cn);
    }
  }
}

__global__ __launch_bounds__(256) void k_out(const float* __restrict__ h,
                                             float* __restrict__ out) {
  const int i = blockIdx.x * 256 + threadIdx.x;  // B*H
  const int b = i >> 8, t = i & 255;
  out[i] = h[((size_t)b * NN) * NH + t];
}

// ======================= launch =======================
extern "C" void kernel_launch(void* const* d_in, const int* in_sizes, int n_in,
                              void* d_out, int out_size, void* d_ws, size_t ws_size,
                              hipStream_t stream) {
  (void)in_sizes; (void)n_in; (void)out_size;
  const float* nf     = (const float*)d_in[0];
  const float* W_enc  = (const float*)d_in[1];
  const float* b_enc  = (const float*)d_in[2];
  const float* rel_emb= (const float*)d_in[3];
  const float* W_i    = (const float*)d_in[4];
  const float* b_i    = (const float*)d_in[5];
  const float* W_o    = (const float*)d_in[6];
  const float* b_o    = (const float*)d_in[7];
  const float* W_u    = (const float*)d_in[8];
  const float* b_u    = (const float*)d_in[9];
  const float* W_f    = (const float*)d_in[10];
  const float* b_f    = (const float*)d_in[11];
  const float* w_attn = (const float*)d_in[12];
  const float* b_attn = (const float*)d_in[13];
  float* out = (float*)d_out;

  static HostTree T;          // rebuilt identically every call (deterministic)
  build_tree_host(T);

  char* ws = (char*)d_ws;
  const size_t OFF_H = 16 * 1024;
  const size_t SZ_HC = (size_t)NB * NN * NH * sizeof(float);  // 67 MB
  const size_t OFF_C = OFF_H + SZ_HC;
  const size_t OFF_COMB = OFF_C + SZ_HC;
  TreeMeta* dm = (TreeMeta*)ws;
  float* h = (float*)(ws + OFF_H);
  float* c = (float*)(ws + OFF_C);
  float* comb = (float*)(ws + OFF_COMB);

  // chunk size bounded by remaining workspace
  int chunk = 64;
  if (ws_size > OFF_COMB) {
    size_t avail = ws_size - OFF_COMB;
    size_t per = (size_t)NB * 2 * NH * sizeof(float);
    int mc = (int)(avail / per);
    if (mc < chunk) chunk = mc > 0 ? mc : 1;
  }

  hipMemcpyAsync(dm, &T.meta, sizeof(TreeMeta), hipMemcpyHostToDevice, stream);
  hipMemsetAsync(c, 0, SZ_HC, stream);

  k_encoder<<<dim3((NB * NN) / 64, NH / 64), 256, 0, stream>>>(nf, W_enc, b_enc, h);

  for (int l = 0; l < T.n_levels; l++) {
    const int off = T.level_off[l], M = T.level_M[l];
    for (int c0 = 0; c0 < M; c0 += chunk) {
      const int Mc = (M - c0) < chunk ? (M - c0) : chunk;
      const int nb = off + c0;
      k_attn<<<dim3(Mc, NB), 256, 0, stream>>>(h, rel_emb, w_attn, b_attn, comb,
          dm->nodes, dm->cstart, dm->ccount, dm->echild, dm->erel, dm->edecay,
          nb, Mc);
      k_csum<<<dim3(Mc, 8), 256, 0, stream>>>(h, c, W_f, b_f,
          dm->nodes, dm->cstart, dm->ccount, dm->echild, dm->erel, dm->edecay,
          nb);
      k_gates<<<dim3(Mc, 8), 256, 0, stream>>>(comb, W_i, b_i, W_o, b_o, W_u,
          b_u, h, c, dm->nodes, nb, Mc);
    }
  }
  k_out<<<dim3((NB * NH) / 256), 256, 0, stream>>>(h, out);
}

// Round 2
// 1202.228 us; speedup vs baseline: 2.2010x; 2.2010x over previous
//
#include <hip/hip_runtime.h>
#include <stdint.h>
#include <string.h>
#include <math.h>

#define NB 128   // batch
#define NN 512   // nodes
#define NH 256   // hidden
#define NR 3

typedef __attribute__((ext_vector_type(8))) short bh8;   // 8 x bf16
typedef __attribute__((ext_vector_type(4))) float f32x4;

// ======================= numpy RNG reproduction (host) =======================
struct Pcg {
  __uint128_t state, inc;
  bool has32; uint32_t buf32;
};

static const __uint128_t PCG_MULT =
    (((__uint128_t)2549297995355413924ULL) << 64) | 4865540595714422341ULL;

static inline uint64_t pcg_next64(Pcg& s) {
  s.state = s.state * PCG_MULT + s.inc;
  uint64_t hi = (uint64_t)(s.state >> 64), lo = (uint64_t)s.state;
  uint64_t x = hi ^ lo;
  unsigned rot = (unsigned)(s.state >> 122) & 63u;
  return (x >> rot) | (x << ((64u - rot) & 63u));
}
static inline uint32_t pcg_next32(Pcg& s) {
  if (s.has32) { s.has32 = false; return s.buf32; }
  uint64_t n = pcg_next64(s);
  s.has32 = true; s.buf32 = (uint32_t)(n >> 32);
  return (uint32_t)n;
}
static inline uint64_t pcg_bounded(Pcg& s, uint64_t high) {
  uint64_t rng = high - 1;
  if (rng == 0) return 0;
  uint32_t rng_excl = (uint32_t)rng + 1u;
  uint64_t m = (uint64_t)pcg_next32(s) * (uint64_t)rng_excl;
  uint32_t leftover = (uint32_t)m;
  if (leftover < rng_excl) {
    uint32_t threshold = (uint32_t)((0xFFFFFFFFu - (uint32_t)rng) % rng_excl);
    while (leftover < threshold) {
      m = (uint64_t)pcg_next32(s) * (uint64_t)rng_excl;
      leftover = (uint32_t)m;
    }
  }
  return m >> 32;
}
static inline double pcg_double(Pcg& s) {
  return (double)(pcg_next64(s) >> 11) * (1.0 / 9007199254740992.0);
}

static void pcg_seed0(Pcg& s) {
  uint32_t pool[4];
  uint32_t hc = 0x43b0d7e5u;
  auto hashmix = [&hc](uint32_t v) -> uint32_t {
    v ^= hc; hc *= 0x931e8875u; v *= hc; v ^= v >> 16; return v;
  };
  auto mix = [](uint32_t x, uint32_t y) -> uint32_t {
    uint32_t r = 0xca01f9ddu * x - 0x4973f715u * y; r ^= r >> 16; return r;
  };
  for (int i = 0; i < 4; i++) pool[i] = hashmix(0u);
  for (int src = 0; src < 4; src++)
    for (int dst = 0; dst < 4; dst++)
      if (src != dst) pool[dst] = mix(pool[dst], hashmix(pool[src]));
  uint32_t gs[8]; uint32_t hb = 0x8b51f9ddu;
  for (int i = 0; i < 8; i++) {
    uint32_t dv = pool[i & 3];
    dv ^= hb; hb *= 0x58f38dedu; dv *= hb; dv ^= dv >> 16;
    gs[i] = dv;
  }
  uint64_t w0 = (uint64_t)gs[0] | ((uint64_t)gs[1] << 32);
  uint64_t w1 = (uint64_t)gs[2] | ((uint64_t)gs[3] << 32);
  uint64_t w2 = (uint64_t)gs[4] | ((uint64_t)gs[5] << 32);
  uint64_t w3 = (uint64_t)gs[6] | ((uint64_t)gs[7] << 32);
  __uint128_t initstate = (((__uint128_t)w0) << 64) | w1;
  __uint128_t initseq   = (((__uint128_t)w2) << 64) | w3;
  s.state = 0;
  s.inc = (initseq << 1) | 1;
  s.state = s.state * PCG_MULT + s.inc;
  s.state += initstate;
  s.state = s.state * PCG_MULT + s.inc;
  s.has32 = false; s.buf32 = 0;
}

// ======================= tree build (host) =======================
struct TreeMeta {
  int nodes[512];    // internal nodes, level-ordered (deepest first)
  int cstart[512];
  int ccount[512];
  int echild[512];   // all-children edges, node-grouped
  int erel[512];
  float edecay[512];
  int cechild[512];  // csum edges: internal-child only
  int cepar[512];    // parent NODE ID
  int cerel[512];
  float cedec[512];
};
struct HostTree {
  TreeMeta meta;
  int n_levels;
  int level_off[520];
  int level_M[520];
  int ce_node_start[513];  // per meta-node index -> first csum edge (+sentinel)
};

static void build_tree_host(HostTree& T) {
  Pcg st; pcg_seed0(st);
  int parent[NN], depth[NN], rel[NN];
  unsigned char virt[NN];
  parent[0] = 0; depth[0] = 0;
  for (int i = 1; i < NN; i++) parent[i] = (int)pcg_bounded(st, (uint64_t)i);
  for (int i = 1; i < NN; i++) depth[i] = depth[parent[i]] + 1;
  for (int i = 0; i < NN; i++) rel[i] = (int)pcg_bounded(st, (uint64_t)NR);
  for (int i = 0; i < NN; i++) virt[i] = (pcg_double(st) < 0.1) ? 1 : 0;

  int childcnt[NN]; memset(childcnt, 0, sizeof(childcnt));
  for (int i = 1; i < NN; i++) childcnt[parent[i]]++;
  int maxd = 0;
  for (int i = 0; i < NN; i++) if (depth[i] > maxd) maxd = depth[i];

  int ni = 0, ne = 0, nec = 0;
  T.n_levels = 0;
  for (int d = maxd; d >= 0; d--) {
    int mstart = ni;
    for (int n = 0; n < NN; n++) {
      if (depth[n] == d && childcnt[n] > 0) {
        T.meta.nodes[ni] = n;
        T.meta.cstart[ni] = ne;
        T.meta.ccount[ni] = childcnt[n];
        T.ce_node_start[ni] = nec;
        for (int i2 = 1; i2 < NN; i2++) {
          if (parent[i2] == n) {
            T.meta.echild[ne] = i2;
            T.meta.erel[ne] = rel[i2];
            T.meta.edecay[ne] = virt[i2] ? 0.7f : 1.0f;
            ne++;
            if (childcnt[i2] > 0) {  // leaf children contribute exactly 0 to c_sum
              T.meta.cechild[nec] = i2;
              T.meta.cepar[nec] = n;
              T.meta.cerel[nec] = rel[i2];
              T.meta.cedec[nec] = virt[i2] ? 0.7f : 1.0f;
              nec++;
            }
          }
        }
        ni++;
      }
    }
    if (ni > mstart) {
      T.level_off[T.n_levels] = mstart;
      T.level_M[T.n_levels] = ni - mstart;
      T.n_levels++;
    }
  }
  T.ce_node_start[ni] = nec;
}

// ======================= device helpers =======================
__device__ __forceinline__ uint16_t f2bf(float f) {
  uint32_t u = __float_as_uint(f);
  return (uint16_t)((u + 0x7fffu + ((u >> 16) & 1u)) >> 16);
}
__device__ __forceinline__ float bf2f(uint16_t b) {
  return __uint_as_float(((uint32_t)b) << 16);
}

// Stage a rows x 64 bf16 tile into LDS with XOR swizzle (T2): elem ^= (row&7)<<3
__device__ __forceinline__ void stage_bf16(uint16_t* __restrict__ sm,
    const uint16_t* __restrict__ src, int stride, int rows) {
  const int chunks = rows << 3;
  for (int cch = threadIdx.x; cch < chunks; cch += 256) {
    const int row = cch >> 3, k = (cch & 7) << 3;
    uint4 v = *(const uint4*)(src + (size_t)row * stride + k);
    *(uint4*)(sm + (((row << 6) + k) ^ ((row & 7) << 3))) = v;
  }
}
// Same but fp32 source, converting to bf16
__device__ __forceinline__ void stage_f32(uint16_t* __restrict__ sm,
    const float* __restrict__ src, int stride, int rows) {
  const int chunks = rows << 3;
  for (int cch = threadIdx.x; cch < chunks; cch += 256) {
    const int row = cch >> 3, k = (cch & 7) << 3;
    const float* p = src + (size_t)row * stride + k;
    float4 a = *(const float4*)p, b = *(const float4*)(p + 4);
    uint4 w;
    w.x = (uint32_t)f2bf(a.x) | ((uint32_t)f2bf(a.y) << 16);
    w.y = (uint32_t)f2bf(a.z) | ((uint32_t)f2bf(a.w) << 16);
    w.z = (uint32_t)f2bf(b.x) | ((uint32_t)f2bf(b.y) << 16);
    w.w = (uint32_t)f2bf(b.z) | ((uint32_t)f2bf(b.w) << 16);
    *(uint4*)(sm + (((row << 6) + k) ^ ((row & 7) << 3))) = w;
  }
}
__device__ __forceinline__ bh8 fld(const uint16_t* __restrict__ sm, int row, int k) {
  return *(const bh8*)(sm + (((row << 6) + k) ^ ((row & 7) << 3)));
}

// ======================= weight prep: transpose + bf16 =======================
__global__ __launch_bounds__(256) void k_prep(const float* __restrict__ We,
    const float* __restrict__ Wf, const float* __restrict__ Wi,
    const float* __restrict__ Wo, const float* __restrict__ Wu,
    uint16_t* __restrict__ WeT, uint16_t* __restrict__ WfT,
    uint16_t* __restrict__ WgT) {
  const int i = blockIdx.x * 256 + threadIdx.x;
  if (i < 65536) {
    const int n = i >> 8, k = i & 255;
    WeT[i] = f2bf(We[k * 256 + n]);
  }
  const int i2 = i - 65536;
  if (i2 >= 0 && i2 < 196608) {
    const int r = i2 >> 16, rem = i2 & 65535, n = rem >> 8, k = rem & 255;
    WfT[i2] = f2bf(Wf[r * 65536 + k * 256 + n]);
  }
  const int i3 = i - 262144;
  if (i3 >= 0 && i3 < 393216) {
    const int g = i3 >> 17, rem = i3 & 131071, n = rem >> 9, k = rem & 511;
    const float* S = (g == 0) ? Wi : (g == 1) ? Wo : Wu;
    WgT[i3] = f2bf(S[k * 256 + n]);
  }
}

// ======================= encoder: h_bf = bf16(nf @ W_enc + b) =======================
__global__ __launch_bounds__(256) void k_enc(const float* __restrict__ nf,
    const uint16_t* __restrict__ WeT, const float* __restrict__ b_enc,
    uint16_t* __restrict__ h_bf) {
  __shared__ __align__(16) uint16_t smA[128 * 64];
  __shared__ __align__(16) uint16_t smB[128 * 64];
  const int bm = blockIdx.x * 128, bn = blockIdx.y * 128;
  const int tid = threadIdx.x, wid = tid >> 6, lane = tid & 63;
  const int wr = wid >> 1, wc2 = wid & 1, lr = lane & 15, lk = (lane >> 4) << 3;
  f32x4 acc[4][4] = {};
  for (int k0 = 0; k0 < 256; k0 += 64) {
    __syncthreads();
    stage_f32(smA, nf + (size_t)bm * NH + k0, NH, 128);
    stage_bf16(smB, WeT + (size_t)bn * 256 + k0, 256, 128);
    __syncthreads();
#pragma unroll
    for (int ks = 0; ks < 2; ks++) {
      bh8 af[4], bfr[4];
#pragma unroll
      for (int i = 0; i < 4; i++) af[i] = fld(smA, wr * 64 + i * 16 + lr, ks * 32 + lk);
#pragma unroll
      for (int j = 0; j < 4; j++) bfr[j] = fld(smB, wc2 * 64 + j * 16 + lr, ks * 32 + lk);
#pragma unroll
      for (int i = 0; i < 4; i++)
#pragma unroll
        for (int j = 0; j < 4; j++)
          acc[i][j] = __builtin_amdgcn_mfma_f32_16x16x32_bf16(af[i], bfr[j], acc[i][j], 0, 0, 0);
    }
  }
#pragma unroll
  for (int i = 0; i < 4; i++) {
#pragma unroll
    for (int j = 0; j < 4; j++) {
      const int col = bn + wc2 * 64 + j * 16 + (lane & 15);
      const float be = b_enc[col];
#pragma unroll
      for (int r = 0; r < 4; r++) {
        const int row = bm + wr * 64 + i * 16 + (lane >> 4) * 4 + r;
        h_bf[(size_t)row * NH + col] = f2bf(acc[i][j][r] + be);
      }
    }
  }
}

// ======================= fused attn + csum (one launch per level chunk) =======================
__global__ __launch_bounds__(256) void k_ac(
    const uint16_t* __restrict__ h_bf, float* __restrict__ c,
    const uint16_t* __restrict__ WfT, const float* __restrict__ b_f,
    const float* __restrict__ rel_emb, const float* __restrict__ w_attn,
    const float* __restrict__ b_attn, uint16_t* __restrict__ comb,
    const int* __restrict__ nodes, const int* __restrict__ cstart,
    const int* __restrict__ ccount, const int* __restrict__ echild,
    const int* __restrict__ erel, const float* __restrict__ edecay,
    const int* __restrict__ cechild, const int* __restrict__ cepar,
    const int* __restrict__ cerel, const float* __restrict__ cedec,
    int nb, int cebase, int nCE, int Mc) {
  __shared__ __align__(16) char smem[33024];
  const int tid = threadIdx.x;
  if ((int)blockIdx.x < 2 * nCE) {
    // ---------- csum role: one edge x 128-col tile; G = (dec*h_ch)@W_f[r] ----------
    uint16_t* smA = (uint16_t*)smem;
    uint16_t* smB = (uint16_t*)(smem + 16384);
    const int ce = cebase + ((int)blockIdx.x >> 1);
    const int n0 = ((int)blockIdx.x & 1) * 128;
    const int child = cechild[ce], par = cepar[ce], rel = cerel[ce];
    const float dec = cedec[ce];
    const int wid = tid >> 6, lane = tid & 63;
    const int wr = wid >> 1, wc2 = wid & 1, lr = lane & 15, lk = (lane >> 4) << 3;
    f32x4 acc[4][4] = {};
    for (int k0 = 0; k0 < 256; k0 += 64) {
      __syncthreads();
      stage_bf16(smA, h_bf + (size_t)child * NH + k0, NN * NH, 128);
      stage_bf16(smB, WfT + (size_t)rel * 65536 + (size_t)n0 * 256 + k0, 256, 128);
      __syncthreads();
#pragma unroll
      for (int ks = 0; ks < 2; ks++) {
        bh8 af[4], bfr[4];
#pragma unroll
        for (int i = 0; i < 4; i++) af[i] = fld(smA, wr * 64 + i * 16 + lr, ks * 32 + lk);
#pragma unroll
        for (int j = 0; j < 4; j++) bfr[j] = fld(smB, wc2 * 64 + j * 16 + lr, ks * 32 + lk);
#pragma unroll
        for (int i = 0; i < 4; i++)
#pragma unroll
          for (int j = 0; j < 4; j++)
            acc[i][j] = __builtin_amdgcn_mfma_f32_16x16x32_bf16(af[i], bfr[j], acc[i][j], 0, 0, 0);
      }
    }
#pragma unroll
    for (int i = 0; i < 4; i++) {
#pragma unroll
      for (int j = 0; j < 4; j++) {
        const int col = n0 + wc2 * 64 + j * 16 + (lane & 15);
        const float bf_ = b_f[rel * NH + col];
#pragma unroll
        for (int r = 0; r < 4; r++) {
          const int b = wr * 64 + i * 16 + (lane >> 4) * 4 + r;
          const float f = dec * acc[i][j][r] + bf_;
          const float cc_ = c[((size_t)b * NN + child) * NH + col] * dec;
          atomicAdd(&c[((size_t)b * NN + par) * NH + col], f * cc_);
        }
      }
    }
  } else {
    // ---------- attn role: node mloc, 32 batches ----------
    float* sc = (float*)smem;                  // [32][64]
    float* aw = (float*)(smem + 8192);         // [32][64]
    float* RE = (float*)(smem + 16384);        // [3]
    int* chl = (int*)(smem + 16400);           // [64]
    int* rll = (int*)(smem + 16656);           // [64]
    float* dcl = (float*)(smem + 16912);       // [64]
    const int bi2 = (int)blockIdx.x - 2 * nCE;
    const int mloc = bi2 >> 2, bq = bi2 & 3;
    const int b0 = bq * 32;
    const int nd = nodes[nb + mloc];
    const int cs = cstart[nb + mloc], cc = ccount[nb + mloc];
    if (tid < cc) {
      chl[tid] = echild[cs + tid];
      rll[tid] = erel[cs + tid];
      dcl[tid] = edecay[cs + tid];
    }
    const int wid = tid >> 6, lane = tid & 63;
    if (wid < 3) {  // RE[r] = sum_t rel_emb[r]*w_attn
      float p = 0.f;
#pragma unroll
      for (int i = 0; i < 4; i++) p += rel_emb[wid * NH + lane + 64 * i] * w_attn[lane + 64 * i];
#pragma unroll
      for (int off = 32; off; off >>= 1) p += __shfl_down(p, off);
      if (lane == 0) RE[wid] = p;
    }
    __syncthreads();
    // scores: 8 lanes per batch
    const int b8 = tid >> 3, sub = tid & 7;
    float wav[32];
#pragma unroll
    for (int i = 0; i < 32; i++) wav[i] = w_attn[sub + (i << 3)];
    const float ba = b_attn[0];
    for (int e = 0; e < cc; e++) {
      const uint16_t* hp = h_bf + ((size_t)(b0 + b8) * NN + chl[e]) * NH + sub;
      float s = 0.f;
#pragma unroll
      for (int i = 0; i < 32; i++) s = fmaf(bf2f(hp[i << 3]), wav[i], s);
      s += __shfl_xor(s, 1); s += __shfl_xor(s, 2); s += __shfl_xor(s, 4);
      if (sub == 0) sc[b8 * 64 + e] = RE[rll[e]] + dcl[e] * s + ba;
    }
    __syncthreads();
    if (tid < 32) {  // softmax per batch; fold decay into weight
      float mx = -1e30f;
      for (int e = 0; e < cc; e++) mx = fmaxf(mx, sc[tid * 64 + e]);
      float sm_ = 0.f;
      for (int e = 0; e < cc; e++) sm_ += expf(sc[tid * 64 + e] - mx);
      const float inv = 1.0f / sm_;
      for (int e = 0; e < cc; e++) aw[tid * 64 + e] = expf(sc[tid * 64 + e] - mx) * inv * dcl[e];
    }
    __syncthreads();
    // comb = [x, h_sum] (bf16), rows b, K=512
    for (int bi = 0; bi < 32; bi++) {
      const int b = b0 + bi;
      float a2 = 0.f;
      for (int e = 0; e < cc; e++)
        a2 = fmaf(aw[bi * 64 + e], bf2f(h_bf[((size_t)b * NN + chl[e]) * NH + tid]), a2);
      uint16_t* cb = comb + ((size_t)(mloc * 128 + b)) * 512;
      cb[tid] = h_bf[((size_t)b * NN + nd) * NH + tid];
      cb[256 + tid] = f2bf(a2);
    }
  }
}

// ======================= gates: i/o/u GEMM (K=512) + LSTM epilogue =======================
__global__ __launch_bounds__(256) void k_gates(
    const uint16_t* __restrict__ comb, const uint16_t* __restrict__ WgT,
    const float* __restrict__ b_i, const float* __restrict__ b_o,
    const float* __restrict__ b_u, float* __restrict__ c,
    uint16_t* __restrict__ h_bf, float* __restrict__ out,
    const int* __restrict__ nodes, int nb) {
  __shared__ __align__(16) uint16_t smA[128 * 64];
  __shared__ __align__(16) uint16_t smB[3 * 64 * 64];
  const int mloc = blockIdx.x, n0 = blockIdx.y * 64;
  const int nd = nodes[nb + mloc];
  const int tid = threadIdx.x, wid = tid >> 6, lane = tid & 63;
  const int wr = wid >> 1, wc2 = wid & 1, lr = lane & 15, lk = (lane >> 4) << 3;
  f32x4 acc[3][4][2] = {};
  for (int k0 = 0; k0 < 512; k0 += 64) {
    __syncthreads();
    stage_bf16(smA, comb + (size_t)mloc * 128 * 512 + k0, 512, 128);
#pragma unroll
    for (int g = 0; g < 3; g++)
      stage_bf16(smB + g * 4096, WgT + ((size_t)g << 17) + (size_t)n0 * 512 + k0, 512, 64);
    __syncthreads();
#pragma unroll
    for (int ks = 0; ks < 2; ks++) {
      bh8 af[4], bfr[3][2];
#pragma unroll
      for (int i = 0; i < 4; i++) af[i] = fld(smA, wr * 64 + i * 16 + lr, ks * 32 + lk);
#pragma unroll
      for (int g = 0; g < 3; g++)
#pragma unroll
        for (int j = 0; j < 2; j++)
          bfr[g][j] = fld(smB + g * 4096, wc2 * 32 + j * 16 + lr, ks * 32 + lk);
#pragma unroll
      for (int g = 0; g < 3; g++)
#pragma unroll
        for (int i = 0; i < 4; i++)
#pragma unroll
          for (int j = 0; j < 2; j++)
            acc[g][i][j] = __builtin_amdgcn_mfma_f32_16x16x32_bf16(af[i], bfr[g][j], acc[g][i][j], 0, 0, 0);
    }
  }
#pragma unroll
  for (int i = 0; i < 4; i++) {
#pragma unroll
    for (int j = 0; j < 2; j++) {
      const int col = n0 + wc2 * 32 + j * 16 + (lane & 15);
      const float bi_ = b_i[col], bo_ = b_o[col], bu_ = b_u[col];
#pragma unroll
      for (int r = 0; r < 4; r++) {
        const int b = wr * 64 + i * 16 + (lane >> 4) * 4 + r;
        const float ig = 1.f / (1.f + expf(-(acc[0][i][j][r] + bi_)));
        const float og = 1.f / (1.f + expf(-(acc[1][i][j][r] + bo_)));
        const float ug = tanhf(acc[2][i][j][r] + bu_);
        const size_t idx = ((size_t)b * NN + nd) * NH + col;
        const float cn = fmaf(ig, ug, c[idx]);
        c[idx] = cn;
        const float hn = og * tanhf(cn);
        h_bf[idx] = f2bf(hn);
        if (nd == 0) out[(size_t)b * NH + col] = hn;
      }
    }
  }
}

// ======================= launch =======================
extern "C" void kernel_launch(void* const* d_in, const int* in_sizes, int n_in,
                              void* d_out, int out_size, void* d_ws, size_t ws_size,
                              hipStream_t stream) {
  (void)in_sizes; (void)n_in; (void)out_size; (void)ws_size;
  const float* nf      = (const float*)d_in[0];
  const float* W_enc   = (const float*)d_in[1];
  const float* b_enc   = (const float*)d_in[2];
  const float* rel_emb = (const float*)d_in[3];
  const float* W_i     = (const float*)d_in[4];
  const float* b_i     = (const float*)d_in[5];
  const float* W_o     = (const float*)d_in[6];
  const float* b_o     = (const float*)d_in[7];
  const float* W_u     = (const float*)d_in[8];
  const float* b_u     = (const float*)d_in[9];
  const float* W_f     = (const float*)d_in[10];
  const float* b_f     = (const float*)d_in[11];
  const float* w_attn  = (const float*)d_in[12];
  const float* b_attn  = (const float*)d_in[13];
  float* out = (float*)d_out;

  static HostTree T;  // rebuilt identically every call (deterministic)
  build_tree_host(T);

  char* ws = (char*)d_ws;
  const size_t OFF_C    = 32768;
  const size_t SZ_C     = (size_t)NB * NN * NH * 4;      // 67 MB fp32
  const size_t OFF_HBF  = OFF_C + SZ_C;
  const size_t SZ_HBF   = (size_t)NB * NN * NH * 2;      // 33.5 MB bf16
  const size_t OFF_COMB = OFF_HBF + SZ_HBF;
  const size_t SZ_COMB  = (size_t)64 * 128 * 512 * 2;    // 8 MB
  const size_t OFF_WET  = OFF_COMB + SZ_COMB;
  const size_t OFF_WFT  = OFF_WET + 131072;
  const size_t OFF_WGT  = OFF_WFT + 393216;

  TreeMeta* dm = (TreeMeta*)ws;
  float* c = (float*)(ws + OFF_C);
  uint16_t* h_bf = (uint16_t*)(ws + OFF_HBF);
  uint16_t* comb = (uint16_t*)(ws + OFF_COMB);
  uint16_t* WeT = (uint16_t*)(ws + OFF_WET);
  uint16_t* WfT = (uint16_t*)(ws + OFF_WFT);
  uint16_t* WgT = (uint16_t*)(ws + OFF_WGT);

  hipMemcpyAsync(dm, &T.meta, sizeof(TreeMeta), hipMemcpyHostToDevice, stream);
  hipMemsetAsync(c, 0, SZ_C, stream);

  k_prep<<<2560, 256, 0, stream>>>(W_enc, W_f, W_i, W_o, W_u, WeT, WfT, WgT);
  k_enc<<<dim3((NB * NN) / 128, 2), 256, 0, stream>>>(nf, WeT, b_enc, h_bf);

  for (int l = 0; l < T.n_levels; l++) {
    const int off = T.level_off[l], M = T.level_M[l];
    for (int c0 = 0; c0 < M; c0 += 64) {
      const int Mc = (M - c0) < 64 ? (M - c0) : 64;
      const int nb = off + c0;
      const int cebase = T.ce_node_start[nb];
      const int nCE = T.ce_node_start[nb + Mc] - cebase;
      k_ac<<<dim3(2 * nCE + 4 * Mc), 256, 0, stream>>>(h_bf, c, WfT, b_f,
          rel_emb, w_attn, b_attn, comb,
          dm->nodes, dm->cstart, dm->ccount, dm->echild, dm->erel, dm->edecay,
          dm->cechild, dm->cepar, dm->cerel, dm->cedec,
          nb, cebase, nCE, Mc);
      k_gates<<<dim3(Mc, 4), 256, 0, stream>>>(comb, WgT, b_i, b_o, b_u,
          c, h_bf, out, dm->nodes, nb);
    }
  }
}